// Round 5
// baseline (590.296 us; speedup 1.0000x reference)
//
#include <hip/hip_runtime.h>
#include <stdint.h>

// Problem constants (fixed by reference: L=1024, B=8, D=2048)
#define L_SEQ 1024
#define BATCH 8
#define DIM   2048
#define GM    8192   // L*B
#define GN    6144   // 3*D
#define GK    2048   // D
#define SCALE_X 1.7320508075688772f  // sqrt(1 + 2*exp(0))

using bf16x8  = __attribute__((ext_vector_type(8))) __bf16;
using floatx4 = __attribute__((ext_vector_type(4))) float;

__device__ __forceinline__ unsigned short f2bf(float f) {
  unsigned u = __float_as_uint(f);
  u += 0x7FFFu + ((u >> 16) & 1u);   // round-to-nearest-even
  return (unsigned short)(u >> 16);
}
__device__ __forceinline__ float sigmoidf_fast(float z) {
  return __builtin_amdgcn_rcpf(1.0f + __expf(-z));
}
__device__ __forceinline__ void async16(const unsigned short* g, unsigned short* l) {
  __builtin_amdgcn_global_load_lds(
      (__attribute__((address_space(1))) unsigned int*)g,
      (__attribute__((address_space(3))) unsigned int*)l,
      16, 0, 0);
}

// ---------------- cast x (fp32) -> A (bf16), same layout (GM x GK) -------------
__global__ __launch_bounds__(256) void cast_x_kernel(const float4* __restrict__ xin,
                                                     unsigned short* __restrict__ Aout) {
  const int n4 = (GM * GK) / 4;
  for (int i = blockIdx.x * blockDim.x + threadIdx.x; i < n4; i += gridDim.x * blockDim.x) {
    float4 v = xin[i];
    union { unsigned short s[4]; unsigned long long ll; } o;
    o.s[0] = f2bf(v.x); o.s[1] = f2bf(v.y); o.s[2] = f2bf(v.z); o.s[3] = f2bf(v.w);
    *(unsigned long long*)&Aout[(size_t)i * 4] = o.ll;
  }
}

// ------------- transpose-cast W (GK x GN fp32) -> Bt (GN' x GK bf16) ------------
// Column permutation: W col n = 3d+j -> j==0: Bt row d (u0 plane)
//                                       j>0 : Bt row DIM + 2d + (j-1) (u1u2 pairs)
__global__ __launch_bounds__(256) void transpose_w_kernel(const float* __restrict__ W,
                                                          unsigned short* __restrict__ Bt) {
  __shared__ float tile[32][33];
  const int tx = threadIdx.x & 31, ty = threadIdx.x >> 5;
  const int n0 = blockIdx.x * 32;
  const int k0 = blockIdx.y * 32;
#pragma unroll
  for (int r = 0; r < 32; r += 8)
    tile[ty + r][tx] = W[(size_t)(k0 + ty + r) * GN + n0 + tx];
  __syncthreads();
#pragma unroll
  for (int r = 0; r < 32; r += 8) {
    const int n = n0 + ty + r;
    const int dq = n / 3, j = n - 3 * dq;
    const int np = (j == 0) ? dq : (DIM + 2 * dq + (j - 1));
    Bt[(size_t)np * GK + k0 + tx] = f2bf(tile[tx][ty + r]);
  }
}

// ---------------- GEMM: U = A(GM x GK) * Bt(GN x GK)^T ----------------
// 128x128 block tile, BK=64, XOR-swizzled LDS (conflict-free, r4-verified).
// TRN epilogue: scatter into chain-major U0X[chain][l] = (u0 | x<<16) and
// U12[chain][l] = (u1 | u2<<16) (as shorts). Each 64B line of U0X/U12 is
// covered entirely by one block (block spans 16 consecutive l) -> L2 combines.
template <bool TRN>
__global__ __launch_bounds__(256) void gemm_kernel(const unsigned short* __restrict__ A,
                                                   const unsigned short* __restrict__ Bt,
                                                   unsigned short* __restrict__ U,      // flat (fallback)
                                                   unsigned* __restrict__ U0X,
                                                   unsigned short* __restrict__ U12s,
                                                   const unsigned short* __restrict__ Xbf) {
  __shared__ alignas(16) unsigned short As[128 * 64];
  __shared__ alignas(16) unsigned short Bs[128 * 64];
  const int tid  = threadIdx.x;
  const int wave = tid >> 6, lane = tid & 63;
  const int quad = lane >> 4, lrow = lane & 15;
  const int wm = (wave >> 1) * 64, wn = (wave & 1) * 64;
  const int mBase = blockIdx.y * 128, nBase = blockIdx.x * 128;

  floatx4 acc[4][4] = {};

  const int r  = tid >> 3;
  const int sC = tid & 7;
  const int cg = sC ^ (r & 7);
  const unsigned short* aG0 = A  + (size_t)(mBase + r) * GK + cg * 8;
  const unsigned short* bG0 = Bt + (size_t)(nBase + r) * GK + cg * 8;
  unsigned short* asD = &As[tid * 8];
  unsigned short* bsD = &Bs[tid * 8];
  const int swz = lrow & 7;

  for (int k0 = 0; k0 < GK; k0 += 64) {
#pragma unroll
    for (int i = 0; i < 4; ++i) async16(aG0 + (size_t)i * 32 * GK + k0, asD + i * 2048);
#pragma unroll
    for (int i = 0; i < 4; ++i) async16(bG0 + (size_t)i * 32 * GK + k0, bsD + i * 2048);
    __syncthreads();

#pragma unroll
    for (int kk = 0; kk < 2; ++kk) {
      const int s = (kk * 4 + quad) ^ swz;
      bf16x8 aF[4], bF[4];
#pragma unroll
      for (int t = 0; t < 4; ++t) {
        aF[t] = *(const bf16x8*)&As[(wm + t * 16 + lrow) * 64 + s * 8];
        bF[t] = *(const bf16x8*)&Bs[(wn + t * 16 + lrow) * 64 + s * 8];
      }
#pragma unroll
      for (int mt = 0; mt < 4; ++mt)
#pragma unroll
        for (int nt = 0; nt < 4; ++nt)
          acc[mt][nt] = __builtin_amdgcn_mfma_f32_16x16x32_bf16(aF[mt], bF[nt], acc[mt][nt], 0, 0, 0);
    }
    __syncthreads();
  }

  // C/D layout: col = lane&15 (N), row = quad*4 + reg (M)
  if (TRN) {
    const bool isU0 = (nBase < DIM);   // block-uniform
#pragma unroll
    for (int mt = 0; mt < 4; ++mt) {
      const int gmB = mBase + wm + mt * 16 + quad * 4;
#pragma unroll
      for (int nt = 0; nt < 4; ++nt) {
        const int gn = nBase + wn + nt * 16 + lrow;
#pragma unroll
        for (int q = 0; q < 4; ++q) {
          const int gm = gmB + q;
          const int l = gm >> 3, bb = gm & 7;
          if (isU0) {
            const int chain = bb * DIM + gn;
            const unsigned xs = Xbf[(size_t)gm * GK + gn];
            U0X[(size_t)chain * L_SEQ + l] = (unsigned)f2bf(acc[mt][nt][q]) | (xs << 16);
          } else {
            const int g2 = gn - DIM, dd = g2 >> 1, half = g2 & 1;
            const int chain = bb * DIM + dd;
            U12s[((size_t)chain * L_SEQ + l) * 2 + half] = f2bf(acc[mt][nt][q]);
          }
        }
      }
    }
  } else {
#pragma unroll
    for (int mt = 0; mt < 4; ++mt) {
      const int gm = mBase + wm + mt * 16 + quad * 4;
#pragma unroll
      for (int nt = 0; nt < 4; ++nt) {
        const int gn = nBase + wn + nt * 16 + lrow;
#pragma unroll
        for (int q = 0; q < 4; ++q)
          U[(size_t)(gm + q) * GN + gn] = f2bf(acc[mt][nt][q]);
      }
    }
  }
}

// ---------------- SRU scan (TRN): per-lane CONTIGUOUS streams -------------------
// Chain e reads U0X[e][0..1023] and U12[e][0..1023] (4 KB each, sequential).
// 16-step chunks staged in named uint4 regs, X/Y double buffer -> loads are
// consumed a full chunk-pair (~16-32 steps) after issue; even a per-chunk
// vmcnt drain amortizes latency 16x. No strided address math in the hot loop.
__global__ __launch_bounds__(64) void sru_scan_trn(const unsigned* __restrict__ U0X,
                                                   const unsigned* __restrict__ U12,
                                                   const float* __restrict__ c0,
                                                   const float* __restrict__ wc,
                                                   const float* __restrict__ bias,
                                                   float* __restrict__ out) {
  const int e = blockIdx.x * 64 + threadIdx.x;
  const int b = e >> 11, d = e & (DIM - 1);
  const float vf = wc[d], vr = wc[DIM + d];
  const float bfv = bias[d], brv = bias[DIM + d];
  float c = c0[e];
  constexpr int XS = BATCH * DIM;
  float* hp = out + (size_t)b * DIM + d;

  const uint4* p0 = (const uint4*)(U0X + (size_t)e * L_SEQ);  // 256 uint4
  const uint4* p1 = (const uint4*)(U12 + (size_t)e * L_SEQ);

  uint4 X0[4], X1[4], Y0[4], Y1[4];
#pragma unroll
  for (int i = 0; i < 4; ++i) { X0[i] = p0[i];     X1[i] = p1[i]; }
#pragma unroll
  for (int i = 0; i < 4; ++i) { Y0[i] = p0[4 + i]; Y1[i] = p1[4 + i]; }

#pragma unroll 1
  for (int cb = 0; cb < 32; ++cb) {       // chunks 2cb (X) and 2cb+1 (Y)
    const int nx = (2 * cb + 2) & 63;     // wrap on last iters: re-reads chunk 0/1,
    const int ny = (2 * cb + 3) & 63;     // in-bounds garbage, never consumed
#pragma unroll
    for (int i = 0; i < 4; ++i) {
      const uint4 a = X0[i], u = X1[i];
      X0[i] = p0[nx * 4 + i]; X1[i] = p1[nx * 4 + i];   // refill, used next cb
#pragma unroll
      for (int j = 0; j < 4; ++j) {
        const unsigned ra = (&a.x)[j], rb = (&u.x)[j];
        const float a0 = __uint_as_float(ra << 16);
        const float ax = __uint_as_float(ra & 0xFFFF0000u) * SCALE_X;
        const float u1 = __uint_as_float(rb << 16);
        const float u2 = __uint_as_float(rb & 0xFFFF0000u);
        const float f = sigmoidf_fast(u1 + fmaf(vf, c, bfv));
        c = fmaf(c - a0, f, a0);
        const float rr = sigmoidf_fast(u2 + fmaf(vr, c, brv));
        *hp = fmaf(rr, c - ax, ax);
        hp += XS;
      }
    }
#pragma unroll
    for (int i = 0; i < 4; ++i) {
      const uint4 a = Y0[i], u = Y1[i];
      Y0[i] = p0[ny * 4 + i]; Y1[i] = p1[ny * 4 + i];
#pragma unroll
      for (int j = 0; j < 4; ++j) {
        const unsigned ra = (&a.x)[j], rb = (&u.x)[j];
        const float a0 = __uint_as_float(ra << 16);
        const float ax = __uint_as_float(ra & 0xFFFF0000u) * SCALE_X;
        const float u1 = __uint_as_float(rb << 16);
        const float u2 = __uint_as_float(rb & 0xFFFF0000u);
        const float f = sigmoidf_fast(u1 + fmaf(vf, c, bfv));
        c = fmaf(c - a0, f, a0);
        const float rr = sigmoidf_fast(u2 + fmaf(vr, c, brv));
        *hp = fmaf(rr, c - ax, ax);
        hp += XS;
      }
    }
  }
  out[(size_t)L_SEQ * XS + e] = c;
}

// ---------------- SRU scan (fallback, r3 flat layout) ---------------------------
__global__ __launch_bounds__(64) void sru_scan_flat(const unsigned short* __restrict__ U,
                                                    const unsigned short* __restrict__ xbf,
                                                    const float* __restrict__ c0,
                                                    const float* __restrict__ wc,
                                                    const float* __restrict__ bias,
                                                    float* __restrict__ out) {
  const int e = blockIdx.x * 64 + threadIdx.x;
  const int b = e >> 11, d = e & (DIM - 1);
  const float vf = wc[d], vr = wc[DIM + d];
  const float bfv = bias[d], brv = bias[DIM + d];
  float c = c0[e];

  constexpr int PF = 16;
  constexpr int US = BATCH * GN;
  constexpr int XS = BATCH * DIM;

  const unsigned short* u0p  = U + (size_t)b * GN + d;
  const unsigned short* u12p = U + (size_t)b * GN + DIM + 2 * d;
  const unsigned short* xp   = xbf + (size_t)b * DIM + d;
  float* hp = out + (size_t)b * DIM + d;

  unsigned pu0[PF], pu12[PF], pux[PF];
#pragma unroll
  for (int j = 0; j < PF; ++j) {
    pu0[j]  = u0p[(size_t)j * US];
    pu12[j] = *(const unsigned*)(u12p + (size_t)j * US);
    pux[j]  = xp[(size_t)j * XS];
  }
  const unsigned short* uf0  = u0p + (size_t)PF * US;
  const unsigned short* uf12 = u12p + (size_t)PF * US;
  const unsigned short* xf   = xp + (size_t)PF * XS;

  for (int l0 = 0; l0 < L_SEQ; l0 += PF) {
#pragma unroll
    for (int j = 0; j < PF; ++j) {
      const unsigned r0 = pu0[j], r12 = pu12[j], rx = pux[j];
      pu0[j]  = uf0[0];
      pu12[j] = *(const unsigned*)uf12;
      pux[j]  = xf[0];
      uf0 += US; uf12 += US; xf += XS;
      const float a0 = __uint_as_float(r0 << 16);
      const float u1 = __uint_as_float(r12 << 16);
      const float u2 = __uint_as_float(r12 & 0xFFFF0000u);
      const float ax = __uint_as_float(rx << 16) * SCALE_X;
      const float f = sigmoidf_fast(u1 + fmaf(vf, c, bfv));
      c = fmaf(c - a0, f, a0);
      const float rr = sigmoidf_fast(u2 + fmaf(vr, c, brv));
      *hp = fmaf(rr, c - ax, ax);
      hp += XS;
    }
  }
  out[(size_t)L_SEQ * XS + e] = c;
}

// --------------------------------- launcher ------------------------------------
extern "C" void kernel_launch(void* const* d_in, const int* in_sizes, int n_in,
                              void* d_out, int out_size, void* d_ws, size_t ws_size,
                              hipStream_t stream) {
  const float* x    = (const float*)d_in[0];
  const float* c0   = (const float*)d_in[1];
  const float* W    = (const float*)d_in[2];
  const float* wc   = (const float*)d_in[3];
  const float* bias = (const float*)d_in[4];
  float* out = (float*)d_out;

  char* ws = (char*)d_ws;
  // TRN layout: A 33,554,432 | Bt 25,165,824 | U0X 67,108,864 | U12 67,108,864
  const size_t TRN_NEED = 33554432u + 25165824u + 67108864u + 67108864u;  // 192,937,984

  if (ws_size >= TRN_NEED) {
    unsigned short* A_bf  = (unsigned short*)(ws);
    unsigned short* Bt_bf = (unsigned short*)(ws + 33554432);
    unsigned*       U0X   = (unsigned*)(ws + 58720256);
    unsigned*       U12   = (unsigned*)(ws + 125829120);
    cast_x_kernel<<<4096, 256, 0, stream>>>((const float4*)x, A_bf);
    transpose_w_kernel<<<dim3(GN / 32, GK / 32), 256, 0, stream>>>(W, Bt_bf);
    gemm_kernel<true><<<dim3(GN / 128, GM / 128), 256, 0, stream>>>(
        A_bf, Bt_bf, nullptr, U0X, (unsigned short*)U12, A_bf);
    sru_scan_trn<<<256, 64, 0, stream>>>(U0X, U12, c0, wc, bias, out);
  } else {
    // r3 flat layout (proven): A (+pad) | Bt | U
    unsigned short* A_bf  = (unsigned short*)(ws);
    unsigned short* Bt_bf = (unsigned short*)(ws + 34078720);
    unsigned short* U_bf  = (unsigned short*)(ws + 59244544);
    cast_x_kernel<<<4096, 256, 0, stream>>>((const float4*)x, A_bf);
    transpose_w_kernel<<<dim3(GN / 32, GK / 32), 256, 0, stream>>>(W, Bt_bf);
    gemm_kernel<false><<<dim3(GN / 128, GM / 128), 256, 0, stream>>>(
        A_bf, Bt_bf, U_bf, nullptr, nullptr, nullptr);
    sru_scan_flat<<<256, 64, 0, stream>>>(U_bf, A_bf, c0, wc, bias, out);
  }
}